// Round 5
// baseline (381.971 us; speedup 1.0000x reference)
//
#include <hip/hip_runtime.h>

#define NN 100000
#define NE 1200000
#define D 64
#define NPB 64
#define NBK 391      // ceil(100000/256) buckets of 256 nodes
#define BSH 8        // bucket shift (256 nodes)
#define BMSK 255
#define CAP 4096     // per-bucket capacity (expected 3070, sigma~55)

// ---------------------------------------------------------------------------
// Binning: two-pass per-block LDS histogram; one global atomicAdd per
// (block,bucket) reserves a contiguous run -> coalesced packed writes.
// Record: (dlocal << 20) | src   (src < 2^17, dlocal < 256)
// ---------------------------------------------------------------------------
__global__ __launch_bounds__(256) void k_bin(const int* __restrict__ src,
                                             const int* __restrict__ dst,
                                             int* __restrict__ cur,
                                             int* __restrict__ eidx, int E) {
  __shared__ int lhist[NBK];
  __shared__ int lbase[NBK];
  int tid = threadIdx.x;
  int chunk = (E + gridDim.x - 1) / gridDim.x;
  int e0 = blockIdx.x * chunk;
  int e1 = min(e0 + chunk, E);

  for (int i = tid; i < NBK; i += 256) lhist[i] = 0;
  __syncthreads();
  for (int e = e0 + tid; e < e1; e += 256) atomicAdd(&lhist[dst[e] >> BSH], 1);
  __syncthreads();
  for (int i = tid; i < NBK; i += 256) {
    int c = lhist[i];
    lbase[i] = c ? atomicAdd(&cur[i], c) : 0;
  }
  __syncthreads();
  for (int i = tid; i < NBK; i += 256) lhist[i] = 0;
  __syncthreads();
  for (int e = e0 + tid; e < e1; e += 256) {
    int d = dst[e];
    int b = d >> BSH;
    int r = atomicAdd(&lhist[b], 1);
    int p = lbase[b] + r;
    if (p < CAP) eidx[b * CAP + p] = ((d & BMSK) << 20) | src[e];
  }
}

// ---------------------------------------------------------------------------
// Per-bucket LDS counting sort: one block per bucket. Produces node-sorted
// src list (coalesced write) + per-node off/deg.
// ---------------------------------------------------------------------------
__global__ __launch_bounds__(256) void k_sort(const int* __restrict__ eidx,
                                              const int* __restrict__ cur,
                                              int* __restrict__ sorted,
                                              int* __restrict__ off,
                                              int* __restrict__ deg, int N) {
  __shared__ int recS[CAP];
  __shared__ int srtS[CAP];
  __shared__ int hist[256];
  __shared__ int scan[256];
  __shared__ int cursor[256];

  int b = blockIdx.x;
  int tid = threadIdx.x;
  int cnt = min(cur[b], CAP);
  int ebase = b * CAP;

  for (int i = tid; i < cnt; i += 256) recS[i] = eidx[ebase + i];
  hist[tid] = 0;
  __syncthreads();
  for (int i = tid; i < cnt; i += 256) atomicAdd(&hist[recS[i] >> 20], 1);
  __syncthreads();

  int v = hist[tid];
  scan[tid] = v;
  __syncthreads();
  for (int o = 1; o < 256; o <<= 1) {
    int add = (tid >= o) ? scan[tid - o] : 0;
    __syncthreads();
    scan[tid] += add;
    __syncthreads();
  }
  int excl = scan[tid] - v;
  cursor[tid] = excl;
  __syncthreads();

  for (int i = tid; i < cnt; i += 256) {
    int rec = recS[i];
    int p = atomicAdd(&cursor[rec >> 20], 1);
    srtS[p] = rec & 0xFFFFF;
  }
  __syncthreads();
  for (int i = tid; i < cnt; i += 256) sorted[ebase + i] = srtS[i];

  int node = (b << BSH) + tid;
  if (node < N) {
    off[node] = ebase + excl;
    deg[node] = v;
  }
}

// ---------------------------------------------------------------------------
// Gather-aggregate: agg[i][:] = mean over incoming src rows. 16 lanes/node,
// each lane owns one float4 column slice; 2x unrolled for load overlap.
// ---------------------------------------------------------------------------
__global__ __launch_bounds__(256) void k_aggregate(const float* __restrict__ feat,
                                                   const int* __restrict__ off,
                                                   const int* __restrict__ deg,
                                                   const int* __restrict__ sorted,
                                                   float* __restrict__ agg, int N) {
  int t = blockIdx.x * 256 + threadIdx.x;
  int node = t >> 4;
  if (node >= N) return;
  int lane = t & 15;
  int start = off[node];
  int cnt = deg[node];
  float4 acc = {0.f, 0.f, 0.f, 0.f};
  int j = 0;
  for (; j + 2 <= cnt; j += 2) {
    int s0 = sorted[start + j];
    int s1 = sorted[start + j + 1];
    float4 v0 = ((const float4*)(feat + (size_t)s0 * D))[lane];
    float4 v1 = ((const float4*)(feat + (size_t)s1 * D))[lane];
    acc.x += v0.x + v1.x;
    acc.y += v0.y + v1.y;
    acc.z += v0.z + v1.z;
    acc.w += v0.w + v1.w;
  }
  if (j < cnt) {
    int s0 = sorted[start + j];
    float4 v0 = ((const float4*)(feat + (size_t)s0 * D))[lane];
    acc.x += v0.x; acc.y += v0.y; acc.z += v0.z; acc.w += v0.w;
  }
  float inv = 1.0f / fmaxf((float)cnt, 1.0f);
  acc.x *= inv; acc.y *= inv; acc.z *= inv; acc.w *= inv;
  ((float4*)(agg + (size_t)node * D))[lane] = acc;
}

// ---------------------------------------------------------------------------
// Transform v2: weights live in REGISTERS (lane c owns Wl[c][:], Wr[c][:] =
// 32 float4). Per wave: stage 16 node-rows of agg/x coalesced into a private
// LDS buffer, then per node read rows as LDS *broadcasts* (all lanes same
// addr, conflict-free) and do 128 FMA in 8 independent chains.
// aggsum/out may alias (layer-2 in-place, block reads its rows before write).
// ---------------------------------------------------------------------------
__global__ __launch_bounds__(256) void sage_transform(
    const float* aggsum,
    const float* __restrict__ xin,
    const float* __restrict__ Wl,
    const float* __restrict__ Wr,
    const float* __restrict__ bias,
    float* out,
    int N, int do_relu) {
  __shared__ __align__(16) float As[4][16 * D];   // 16 KB (4 KB/wave)
  __shared__ __align__(16) float Xs[4][16 * D];   // 16 KB

  int tid = threadIdx.x;
  int wave = tid >> 6;
  int lane = tid & 63;

  // one-time: weight rows into registers
  float4 wl[16], wr[16];
  const float4* wlg = (const float4*)(Wl + lane * D);
  const float4* wrg = (const float4*)(Wr + lane * D);
#pragma unroll
  for (int j = 0; j < 16; ++j) { wl[j] = wlg[j]; wr[j] = wrg[j]; }
  float bv = bias[lane];

  int base = blockIdx.x * NPB + wave * 16;   // this wave's 16 nodes
  int nvalid = min(16, N - base);
  if (nvalid <= 0) return;

  // coalesced stage: 16 rows x 64 floats = 256 float4, 4 per lane
  {
    const float4* Ag = (const float4*)(aggsum + (size_t)base * D);
    const float4* Xg = (const float4*)(xin + (size_t)base * D);
    float4* AsW = (float4*)As[wave];
    float4* XsW = (float4*)Xs[wave];
    int lim = nvalid * 16;
#pragma unroll
    for (int i = 0; i < 4; ++i) {
      int p = lane + 64 * i;
      if (p < lim) { AsW[p] = Ag[p]; XsW[p] = Xg[p]; }
    }
  }
  __builtin_amdgcn_wave_barrier();   // order LDS writes before broadcast reads

  for (int n = 0; n < nvalid; ++n) {
    const float4* a4 = (const float4*)(As[wave] + n * D);
    const float4* x4 = (const float4*)(Xs[wave] + n * D);
    float4 accA = {0.f, 0.f, 0.f, 0.f};
    float4 accB = {0.f, 0.f, 0.f, 0.f};
#pragma unroll
    for (int j = 0; j < 16; ++j) {
      float4 a = a4[j], x = x4[j];
      accA.x += a.x * wl[j].x; accA.y += a.y * wl[j].y;
      accA.z += a.z * wl[j].z; accA.w += a.w * wl[j].w;
      accB.x += x.x * wr[j].x; accB.y += x.y * wr[j].y;
      accB.z += x.z * wr[j].z; accB.w += x.w * wr[j].w;
    }
    float acc = bv + (accA.x + accA.y + accA.z + accA.w)
                   + (accB.x + accB.y + accB.z + accB.w);
    if (do_relu) acc = fmaxf(acc, 0.0f);
    out[(size_t)(base + n) * D + lane] = acc;
  }
}

extern "C" void kernel_launch(void* const* d_in, const int* in_sizes, int n_in,
                              void* d_out, int out_size, void* d_ws, size_t ws_size,
                              hipStream_t stream) {
  const float* x   = (const float*)d_in[0];
  const int* edge  = (const int*)d_in[1];
  const float* W1l = (const float*)d_in[2];
  const float* W1r = (const float*)d_in[3];
  const float* b1  = (const float*)d_in[4];
  const float* W2l = (const float*)d_in[5];
  const float* W2r = (const float*)d_in[6];
  const float* b2  = (const float*)d_in[7];
  float* out = (float*)d_out;

  const int N = NN, E = NE;
  const int* src = edge;        // edge_index[0]
  const int* dst = edge + E;    // edge_index[1]

  // workspace: cur[512] | eidx[NBK*CAP] | sorted[NBK*CAP] | off[N] | deg[N] | h[N*D]
  int* cur    = (int*)d_ws;
  int* eidx   = cur + 512;
  int* sorted = eidx + (size_t)NBK * CAP;
  int* off    = sorted + (size_t)NBK * CAP;
  int* deg    = off + N;
  float* h    = (float*)(deg + N);

  const int gridA = (N * 16 + 255) / 256;
  const int gridT = (N + NPB - 1) / NPB;

  hipMemsetAsync(cur, 0, 512 * sizeof(int), stream);
  k_bin<<<192, 256, 0, stream>>>(src, dst, cur, eidx, E);
  k_sort<<<NBK, 256, 0, stream>>>(eidx, cur, sorted, off, deg, N);

  // ---- layer 1: aggregate x -> d_out (scratch), transform -> h ----
  k_aggregate<<<gridA, 256, 0, stream>>>(x, off, deg, sorted, out, N);
  sage_transform<<<gridT, 256, 0, stream>>>(out, x, W1l, W1r, b1, h, N, 1);

  // ---- layer 2: aggregate h -> d_out, transform in-place -> d_out ----
  k_aggregate<<<gridA, 256, 0, stream>>>(h, off, deg, sorted, out, N);
  sage_transform<<<gridT, 256, 0, stream>>>(out, h, W2l, W2r, b2, out, N, 0);
}

// Round 6
// 367.526 us; speedup vs baseline: 1.0393x; 1.0393x over previous
//
#include <hip/hip_runtime.h>

#define NN 100000
#define NE 1200000
#define D 64
#define TNPB 128     // nodes per block in transform (4 waves x 32)
#define NBK 391      // ceil(100000/256) buckets of 256 nodes
#define BSH 8        // bucket shift (256 nodes)
#define BMSK 255
#define CAP 4096     // per-bucket capacity (expected 3070, sigma~55)

// ---------------------------------------------------------------------------
// Binning: two-pass per-block LDS histogram; one global atomicAdd per
// (block,bucket) reserves a contiguous run -> coalesced packed writes.
// Record: (dlocal << 20) | src   (src < 2^17, dlocal < 256)
// ---------------------------------------------------------------------------
__global__ __launch_bounds__(256) void k_bin(const int* __restrict__ src,
                                             const int* __restrict__ dst,
                                             int* __restrict__ cur,
                                             int* __restrict__ eidx, int E) {
  __shared__ int lhist[NBK];
  __shared__ int lbase[NBK];
  int tid = threadIdx.x;
  int chunk = (E + gridDim.x - 1) / gridDim.x;
  int e0 = blockIdx.x * chunk;
  int e1 = min(e0 + chunk, E);

  for (int i = tid; i < NBK; i += 256) lhist[i] = 0;
  __syncthreads();
  for (int e = e0 + tid; e < e1; e += 256) atomicAdd(&lhist[dst[e] >> BSH], 1);
  __syncthreads();
  for (int i = tid; i < NBK; i += 256) {
    int c = lhist[i];
    lbase[i] = c ? atomicAdd(&cur[i], c) : 0;
  }
  __syncthreads();
  for (int i = tid; i < NBK; i += 256) lhist[i] = 0;
  __syncthreads();
  for (int e = e0 + tid; e < e1; e += 256) {
    int d = dst[e];
    int b = d >> BSH;
    int r = atomicAdd(&lhist[b], 1);
    int p = lbase[b] + r;
    if (p < CAP) eidx[b * CAP + p] = ((d & BMSK) << 20) | src[e];
  }
}

// ---------------------------------------------------------------------------
// Per-bucket LDS counting sort: one block per bucket. Produces node-sorted
// src list (coalesced write) + per-node off/deg.
// ---------------------------------------------------------------------------
__global__ __launch_bounds__(256) void k_sort(const int* __restrict__ eidx,
                                              const int* __restrict__ cur,
                                              int* __restrict__ sorted,
                                              int* __restrict__ off,
                                              int* __restrict__ deg, int N) {
  __shared__ int recS[CAP];
  __shared__ int srtS[CAP];
  __shared__ int hist[256];
  __shared__ int scan[256];
  __shared__ int cursor[256];

  int b = blockIdx.x;
  int tid = threadIdx.x;
  int cnt = min(cur[b], CAP);
  int ebase = b * CAP;

  for (int i = tid; i < cnt; i += 256) recS[i] = eidx[ebase + i];
  hist[tid] = 0;
  __syncthreads();
  for (int i = tid; i < cnt; i += 256) atomicAdd(&hist[recS[i] >> 20], 1);
  __syncthreads();

  int v = hist[tid];
  scan[tid] = v;
  __syncthreads();
  for (int o = 1; o < 256; o <<= 1) {
    int add = (tid >= o) ? scan[tid - o] : 0;
    __syncthreads();
    scan[tid] += add;
    __syncthreads();
  }
  int excl = scan[tid] - v;
  cursor[tid] = excl;
  __syncthreads();

  for (int i = tid; i < cnt; i += 256) {
    int rec = recS[i];
    int p = atomicAdd(&cursor[rec >> 20], 1);
    srtS[p] = rec & 0xFFFFF;
  }
  __syncthreads();
  for (int i = tid; i < cnt; i += 256) sorted[ebase + i] = srtS[i];

  int node = (b << BSH) + tid;
  if (node < N) {
    off[node] = ebase + excl;
    deg[node] = v;
  }
}

// ---------------------------------------------------------------------------
// Gather-aggregate: agg[i][:] = mean over incoming src rows. 16 lanes/node,
// each lane owns one float4 column slice; 2x unrolled for load overlap.
// ---------------------------------------------------------------------------
__global__ __launch_bounds__(256) void k_aggregate(const float* __restrict__ feat,
                                                   const int* __restrict__ off,
                                                   const int* __restrict__ deg,
                                                   const int* __restrict__ sorted,
                                                   float* __restrict__ agg, int N) {
  int t = blockIdx.x * 256 + threadIdx.x;
  int node = t >> 4;
  if (node >= N) return;
  int lane = t & 15;
  int start = off[node];
  int cnt = deg[node];
  float4 acc = {0.f, 0.f, 0.f, 0.f};
  int j = 0;
  for (; j + 2 <= cnt; j += 2) {
    int s0 = sorted[start + j];
    int s1 = sorted[start + j + 1];
    float4 v0 = ((const float4*)(feat + (size_t)s0 * D))[lane];
    float4 v1 = ((const float4*)(feat + (size_t)s1 * D))[lane];
    acc.x += v0.x + v1.x;
    acc.y += v0.y + v1.y;
    acc.z += v0.z + v1.z;
    acc.w += v0.w + v1.w;
  }
  if (j < cnt) {
    int s0 = sorted[start + j];
    float4 v0 = ((const float4*)(feat + (size_t)s0 * D))[lane];
    acc.x += v0.x; acc.y += v0.y; acc.z += v0.z; acc.w += v0.w;
  }
  float inv = 1.0f / fmaxf((float)cnt, 1.0f);
  acc.x *= inv; acc.y *= inv; acc.z *= inv; acc.w *= inv;
  ((float4*)(agg + (size_t)node * D))[lane] = acc;
}

// ---------------------------------------------------------------------------
// Transform v3: weights in registers (loaded via coalesced LDS stage, not
// strided global), 32 nodes/wave in two 16-row LDS-staged chunks. Per node:
// 32 LDS broadcast b128 (separate pipe) + 128 v_fma in 8 chains.
// aggsum/out may alias (layer-2 in-place; wave reads its rows before write).
// ---------------------------------------------------------------------------
__global__ __launch_bounds__(256) void sage_transform(
    const float* aggsum,
    const float* __restrict__ xin,
    const float* __restrict__ Wl,
    const float* __restrict__ Wr,
    const float* __restrict__ bias,
    float* out,
    int N, int do_relu) {
  __shared__ __align__(16) float WlS[D * 68];   // 17 KB
  __shared__ __align__(16) float WrS[D * 68];
  __shared__ __align__(16) float As[4][16 * D]; // 16 KB
  __shared__ __align__(16) float Xs[4][16 * D]; // 16 KB

  int tid = threadIdx.x;
  // coalesced weight stage to LDS
  for (int i = tid; i < D * D; i += 256) {
    int c = i >> 6, k = i & 63;
    WlS[c * 68 + k] = Wl[i];
    WrS[c * 68 + k] = Wr[i];
  }
  __syncthreads();

  int wave = tid >> 6;
  int lane = tid & 63;

  // one-time: weight rows LDS -> registers (68*4 bytes stride, 16B aligned)
  float4 wl[16], wr[16];
  const float4* wlp = (const float4*)(WlS + lane * 68);
  const float4* wrp = (const float4*)(WrS + lane * 68);
#pragma unroll
  for (int j = 0; j < 16; ++j) { wl[j] = wlp[j]; wr[j] = wrp[j]; }
  float bv = bias[lane];

  int wbase = blockIdx.x * TNPB + wave * 32;   // this wave's 32 nodes

  for (int c0 = 0; c0 < 32; c0 += 16) {
    int base = wbase + c0;
    int nvalid = min(16, N - base);
    if (nvalid <= 0) break;

    // coalesced stage: 16 rows x 16 float4 = 256 float4, 4 per lane
    const float4* Ag = (const float4*)(aggsum + (size_t)base * D);
    const float4* Xg = (const float4*)(xin + (size_t)base * D);
    float4* AsW = (float4*)As[wave];
    float4* XsW = (float4*)Xs[wave];
    int lim = nvalid * 16;
#pragma unroll
    for (int i = 0; i < 4; ++i) {
      int p = lane + 64 * i;
      if (p < lim) { AsW[p] = Ag[p]; XsW[p] = Xg[p]; }
    }
    __builtin_amdgcn_wave_barrier();   // order LDS writes before broadcast reads

    for (int n = 0; n < nvalid; ++n) {
      const float4* a4 = (const float4*)(As[wave] + n * D);
      const float4* x4 = (const float4*)(Xs[wave] + n * D);
      float4 accA = {0.f, 0.f, 0.f, 0.f};
      float4 accB = {0.f, 0.f, 0.f, 0.f};
#pragma unroll
      for (int j = 0; j < 16; ++j) {
        float4 a = a4[j], x = x4[j];
        accA.x += a.x * wl[j].x; accA.y += a.y * wl[j].y;
        accA.z += a.z * wl[j].z; accA.w += a.w * wl[j].w;
        accB.x += x.x * wr[j].x; accB.y += x.y * wr[j].y;
        accB.z += x.z * wr[j].z; accB.w += x.w * wr[j].w;
      }
      float acc = bv + (accA.x + accA.y + accA.z + accA.w)
                     + (accB.x + accB.y + accB.z + accB.w);
      if (do_relu) acc = fmaxf(acc, 0.0f);
      out[(size_t)(base + n) * D + lane] = acc;
    }
    __builtin_amdgcn_wave_barrier();   // next chunk's ds_writes after reads
  }
}

extern "C" void kernel_launch(void* const* d_in, const int* in_sizes, int n_in,
                              void* d_out, int out_size, void* d_ws, size_t ws_size,
                              hipStream_t stream) {
  const float* x   = (const float*)d_in[0];
  const int* edge  = (const int*)d_in[1];
  const float* W1l = (const float*)d_in[2];
  const float* W1r = (const float*)d_in[3];
  const float* b1  = (const float*)d_in[4];
  const float* W2l = (const float*)d_in[5];
  const float* W2r = (const float*)d_in[6];
  const float* b2  = (const float*)d_in[7];
  float* out = (float*)d_out;

  const int N = NN, E = NE;
  const int* src = edge;        // edge_index[0]
  const int* dst = edge + E;    // edge_index[1]

  // workspace: cur[512] | eidx[NBK*CAP] | sorted[NBK*CAP] | off[N] | deg[N] | h[N*D]
  int* cur    = (int*)d_ws;
  int* eidx   = cur + 512;
  int* sorted = eidx + (size_t)NBK * CAP;
  int* off    = sorted + (size_t)NBK * CAP;
  int* deg    = off + N;
  float* h    = (float*)(deg + N);

  const int gridA = (N * 16 + 255) / 256;
  const int gridT = (N + TNPB - 1) / TNPB;

  hipMemsetAsync(cur, 0, 512 * sizeof(int), stream);
  k_bin<<<192, 256, 0, stream>>>(src, dst, cur, eidx, E);
  k_sort<<<NBK, 256, 0, stream>>>(eidx, cur, sorted, off, deg, N);

  // ---- layer 1: aggregate x -> d_out (scratch), transform -> h ----
  k_aggregate<<<gridA, 256, 0, stream>>>(x, off, deg, sorted, out, N);
  sage_transform<<<gridT, 256, 0, stream>>>(out, x, W1l, W1r, b1, h, N, 1);

  // ---- layer 2: aggregate h -> d_out, transform in-place -> d_out ----
  k_aggregate<<<gridA, 256, 0, stream>>>(h, off, deg, sorted, out, N);
  sage_transform<<<gridT, 256, 0, stream>>>(out, h, W2l, W2r, b2, out, N, 0);
}